// Round 2
// 775.211 us; speedup vs baseline: 2.6867x; 2.6867x over previous
//
#include <hip/hip_runtime.h>
#include <math.h>

// Problem constants
#define B 1024
#define N 100000
#define D 512
#define H 96
#define F 7
#define K 16
#define HF (H*F)            // 672

// GEMM tiling (gmax pass)
#define QT 128              // queries per block
#define KT 128              // keys per block
#define NKT 784             // key tiles (784*128 = 100352)
#define NPAD (NKT*KT)       // 100352 (kb padded with zero rows)

// group-max pruning
#define GQ 32               // keys per group (N = 3125*32 exactly; 11 pad groups)
#define NG (NPAD/GQ)        // 3136 groups per query
#define SELG 16             // groups selected per query (exact: top-16 elems live here)
#define CAND (SELG*GQ)      // 512 gathered candidates
#define CSEL 32             // fp32-rescored candidates

typedef __attribute__((ext_vector_type(8))) short shortx8;   // 8 bf16 (4 VGPRs)
typedef __attribute__((ext_vector_type(4))) float floatx4;   // MFMA accumulator

__device__ __forceinline__ unsigned short f2bf(float f) {    // RTN-even fp32->bf16
    unsigned int u = __float_as_uint(f);
    u += 0x7FFF + ((u >> 16) & 1);
    return (unsigned short)(u >> 16);
}
__device__ __forceinline__ float bf2f(unsigned short u) {
    return __uint_as_float((unsigned)u << 16);
}

// async 16B/lane global->LDS; LDS dest is wave-uniform base + lane*16
#define ASYNC16(g, l) __builtin_amdgcn_global_load_lds( \
    (__attribute__((address_space(1))) void*)(g), \
    (__attribute__((address_space(3))) void*)(l), 16, 0, 0)

// ---------------- prep: normalize queries (fp32 + bf16 copies) ----------------
__global__ void prep_q(const float* __restrict__ q, float* __restrict__ qn,
                       unsigned short* __restrict__ qb) {
    int w = (blockIdx.x * blockDim.x + threadIdx.x) >> 6;   // one wave per row
    int l = threadIdx.x & 63;
    if (w >= B) return;
    const float4* row = (const float4*)(q + (size_t)w * D);
    float4 a = row[l], b = row[l + 64];
    float ss = a.x*a.x + a.y*a.y + a.z*a.z + a.w*a.w
             + b.x*b.x + b.y*b.y + b.z*b.z + b.w*b.w;
#pragma unroll
    for (int off = 32; off; off >>= 1) ss += __shfl_xor(ss, off);
    float nrm = fmaxf(sqrtf(ss), 1e-12f);
    a.x /= nrm; a.y /= nrm; a.z /= nrm; a.w /= nrm;
    b.x /= nrm; b.y /= nrm; b.z /= nrm; b.w /= nrm;
    float4* o = (float4*)(qn + (size_t)w * D);
    o[l] = a; o[l + 64] = b;
    unsigned short* ob = qb + (size_t)w * D;
    *(ushort4*)(ob + 4*l)       = make_ushort4(f2bf(a.x), f2bf(a.y), f2bf(a.z), f2bf(a.w));
    *(ushort4*)(ob + 256 + 4*l) = make_ushort4(f2bf(b.x), f2bf(b.y), f2bf(b.z), f2bf(b.w));
}

// ---------------- prep: kscale fp32 + pre-scaled bf16 keys (zero-padded) ------
__global__ void prep_k(const float* __restrict__ keys, const int* __restrict__ ts,
                       const int* __restrict__ gstep, float* __restrict__ kscale,
                       unsigned short* __restrict__ kb) {
    int w = (blockIdx.x * blockDim.x + threadIdx.x) >> 6;   // one wave per row
    int l = threadIdx.x & 63;
    if (w >= NPAD) return;
    unsigned short* dst = kb + (size_t)w * D;
    if (w >= N) {                                           // zero pad rows -> score 0
        *(ushort4*)(dst + 4*l)       = make_ushort4(0,0,0,0);
        *(ushort4*)(dst + 256 + 4*l) = make_ushort4(0,0,0,0);
        return;
    }
    const float4* row = (const float4*)(keys + (size_t)w * D);
    float4 a = row[l], b = row[l + 64];
    float ss = a.x*a.x + a.y*a.y + a.z*a.z + a.w*a.w
             + b.x*b.x + b.y*b.y + b.z*b.z + b.w*b.w;
#pragma unroll
    for (int off = 32; off; off >>= 1) ss += __shfl_xor(ss, off);
    float age = (float)(gstep[0] - ts[w]);
    float sc = powf(0.995f, age) / fmaxf(sqrtf(ss), 1e-12f);
    if (l == 0) kscale[w] = sc;
    *(ushort4*)(dst + 4*l)       = make_ushort4(f2bf(a.x*sc), f2bf(a.y*sc), f2bf(a.z*sc), f2bf(a.w*sc));
    *(ushort4*)(dst + 256 + 4*l) = make_ushort4(f2bf(b.x*sc), f2bf(b.y*sc), f2bf(b.z*sc), f2bf(b.w*sc));
}

// ---------------- pass 1: bf16 MFMA GEMM -> per-(query, 32-key-group) max ----
// m97 structure: 128x128 tile, BK=32, 2 barriers/K-step, 16 K-steps. No score
// materialization, no scan in the hot loop -- epilogue folds acc to group maxes.
// grid (B/128 = 8, NKT = 784), 256 threads = 4 waves (2q x 2k), each wave a
// 64q x 64k quadrant of 16x16x32 MFMAs (acc[4][4]).
__global__ __launch_bounds__(256, 3)
void gmax_k(const unsigned short* __restrict__ qb, const unsigned short* __restrict__ kb,
            float* __restrict__ gmax) {
    __shared__ __align__(16) unsigned short As[QT * 32];   // 8 KB
    __shared__ __align__(16) unsigned short Bs[KT * 32];   // 8 KB

    const int t = threadIdx.x;
    const int w = t >> 6, l = t & 63;
    const int qbase = blockIdx.x * QT;
    const int kbase = blockIdx.y * KT;
    const int m = l & 15, quad = l >> 4;
    const int wq = w & 1, wk = w >> 1;

    // staging: each ASYNC16 moves 1KB = 16 rows x 64B; wave w owns rows w*32..+31
    const int srow = l >> 2;
    const int scol = (l & 3) * 8;
    const unsigned short* gA0 = qb + (size_t)(qbase + w*32 + srow) * D + scol;
    const unsigned short* gA1 = gA0 + (size_t)16 * D;
    const unsigned short* gB0 = kb + (size_t)(kbase + w*32 + srow) * D + scol;
    const unsigned short* gB1 = gB0 + (size_t)16 * D;
    unsigned short* lA0 = As + (w*32) * 32;      // wave-uniform LDS bases
    unsigned short* lA1 = As + (w*32 + 16) * 32;
    unsigned short* lB0 = Bs + (w*32) * 32;
    unsigned short* lB1 = Bs + (w*32 + 16) * 32;

    // fragment read bases (A-operand layout: row=lane&15, k=quad*8+j)
    const unsigned short* aBase = As + (size_t)(wq*64 + m) * 32 + quad*8;
    const unsigned short* bBase = Bs + (size_t)(wk*64 + m) * 32 + quad*8;

    floatx4 acc[4][4];
#pragma unroll
    for (int i = 0; i < 4; ++i)
#pragma unroll
        for (int j = 0; j < 4; ++j) acc[i][j] = (floatx4){0.f, 0.f, 0.f, 0.f};

    for (int ds = 0; ds < D/32; ++ds) {
        ASYNC16(gA0 + ds*32, lA0);
        ASYNC16(gA1 + ds*32, lA1);
        ASYNC16(gB0 + ds*32, lB0);
        ASYNC16(gB1 + ds*32, lB1);
        __syncthreads();                         // drains vmcnt before barrier
        shortx8 af[4], bf[4];
#pragma unroll
        for (int i = 0; i < 4; ++i) af[i] = *(const shortx8*)(aBase + i*512);
#pragma unroll
        for (int j = 0; j < 4; ++j) bf[j] = *(const shortx8*)(bBase + j*512);
#pragma unroll
        for (int i = 0; i < 4; ++i)
#pragma unroll
            for (int j = 0; j < 4; ++j)
                acc[i][j] = __builtin_amdgcn_mfma_f32_16x16x32_bf16(
                    af[i], bf[j], acc[i][j], 0, 0, 0);
        __syncthreads();                         // reads done before next stage
    }

    // epilogue: C layout col(key)=lane&15, row(query)=quad*4+r.
    // group 0 of this wave = cols 0..31 (kk 0,1), group 1 = cols 32..63 (kk 2,3).
    const int gcol = blockIdx.y * 4 + wk * 2;
#pragma unroll
    for (int qt = 0; qt < 4; ++qt)
#pragma unroll
        for (int r = 0; r < 4; ++r) {
            float v0 = fmaxf(acc[qt][0][r], acc[qt][1][r]);
            float v1 = fmaxf(acc[qt][2][r], acc[qt][3][r]);
#pragma unroll
            for (int off = 1; off < 16; off <<= 1) {     // fold 16 m-lanes
                v0 = fmaxf(v0, __shfl_xor(v0, off));
                v1 = fmaxf(v1, __shfl_xor(v1, off));
            }
            if (m == 0) {
                size_t row = (size_t)(qbase + wq*64 + qt*16 + quad*4 + r);
                gmax[row * NG + gcol]     = v0;
                gmax[row * NG + gcol + 1] = v1;
            }
        }
}

// ---------------- pass 2: per-query select + rescore + softmax + output ------
// top-16 groups by (max desc, idx asc) provably contain the top-16 elements.
__global__ __launch_bounds__(256)
void select_out(const float* __restrict__ gmax, const unsigned short* __restrict__ qb,
                const unsigned short* __restrict__ kb, const float* __restrict__ qn,
                const float* __restrict__ keys, const float* __restrict__ kscale,
                const float* __restrict__ values, float* __restrict__ out) {
    int b = blockIdx.x, t = threadIdx.x;
    __shared__ float sG[NG];                 // 12.5 KB group maxes
    __shared__ int   gSel[SELG];
    __shared__ float eS[CAND];               // gathered candidate scores
    __shared__ int   eI[CAND];               // their global key indices
    __shared__ float rS[4]; __shared__ int rI[4], rP[4];
    __shared__ float qrow[D];                // fp32 normalized q
    __shared__ unsigned short sQ[D];         // bf16 q (consistency with MFMA pass)
    __shared__ float cS[CSEL]; __shared__ int cIdx[CSEL];
    __shared__ float wgt[K]; __shared__ int wIdx[K];

    for (int i = t; i < NG; i += 256) sG[i] = gmax[(size_t)b * NG + i];
    for (int i = t; i < D; i += 256) { qrow[i] = qn[(size_t)b * D + i]; sQ[i] = qb[(size_t)b * D + i]; }
    __syncthreads();

    int lane = t & 63, w = t >> 6;

    // ---- top-16 groups (max desc, group idx asc) ----
    for (int r = 0; r < SELG; ++r) {
        float best = -INFINITY; int bp = 0x7fffffff;
        for (int i = t; i < NG; i += 256) {
            float v = sG[i];
            if (v > best || (v == best && i < bp)) { best = v; bp = i; }
        }
#pragma unroll
        for (int off = 32; off; off >>= 1) {
            float ob = __shfl_xor(best, off);
            int op = __shfl_xor(bp, off);
            if (ob > best || (ob == best && op < bp)) { best = ob; bp = op; }
        }
        if (lane == 0) { rS[w] = best; rP[w] = bp; }
        __syncthreads();
        if (t == 0) {
            float bb = rS[0]; int bbp = rP[0];
            for (int j = 1; j < 4; ++j)
                if (rS[j] > bb || (rS[j] == bb && rP[j] < bbp)) { bb = rS[j]; bbp = rP[j]; }
            gSel[r] = bbp; sG[bbp] = -INFINITY;
        }
        __syncthreads();
    }

    // ---- recompute the 512 gathered candidates (same bf16 inputs as MFMA) ----
    float qv[8];
#pragma unroll
    for (int j = 0; j < 8; ++j) qv[j] = bf2f(sQ[lane*8 + j]);
    for (int s = w; s < CAND; s += 4) {          // wave per candidate, 128 each
        int g = gSel[s >> 5];
        int idx = g * GQ + (s & 31);
        uint4 kv = *(const uint4*)(kb + (size_t)idx * D + lane*8);
        unsigned u0 = kv.x, u1 = kv.y, u2 = kv.z, u3 = kv.w;
        float p = 0.f;
        p = fmaf(qv[0], __uint_as_float((u0 & 0xffffu) << 16), p);
        p = fmaf(qv[1], __uint_as_float(u0 & 0xffff0000u), p);
        p = fmaf(qv[2], __uint_as_float((u1 & 0xffffu) << 16), p);
        p = fmaf(qv[3], __uint_as_float(u1 & 0xffff0000u), p);
        p = fmaf(qv[4], __uint_as_float((u2 & 0xffffu) << 16), p);
        p = fmaf(qv[5], __uint_as_float(u2 & 0xffff0000u), p);
        p = fmaf(qv[6], __uint_as_float((u3 & 0xffffu) << 16), p);
        p = fmaf(qv[7], __uint_as_float(u3 & 0xffff0000u), p);
#pragma unroll
        for (int off = 32; off; off >>= 1) p += __shfl_xor(p, off);
        if (lane == 0) { eS[s] = (idx < N) ? p : -INFINITY; eI[s] = idx; }
    }
    __syncthreads();

    // ---- coarse top-32 elements (score desc, global idx asc) ----
    for (int r = 0; r < CSEL; ++r) {
        float best = -INFINITY; int bi = 0x7fffffff, bp = -1;
        for (int i = t; i < CAND; i += 256) {    // 2 iters
            float v = eS[i]; int ii = eI[i];
            if (v > best || (v == best && ii < bi)) { best = v; bi = ii; bp = i; }
        }
#pragma unroll
        for (int off = 32; off; off >>= 1) {
            float ob = __shfl_xor(best, off);
            int oi = __shfl_xor(bi, off);
            int op = __shfl_xor(bp, off);
            if (ob > best || (ob == best && oi < bi)) { best = ob; bi = oi; bp = op; }
        }
        if (lane == 0) { rS[w] = best; rI[w] = bi; rP[w] = bp; }
        __syncthreads();
        if (t == 0) {
            float bb = rS[0]; int bbi = rI[0], bbp = rP[0];
            for (int j = 1; j < 4; ++j)
                if (rS[j] > bb || (rS[j] == bb && rI[j] < bbi)) { bb = rS[j]; bbi = rI[j]; bbp = rP[j]; }
            cIdx[r] = bbi;
            if (bbp >= 0) eS[bbp] = -INFINITY;
        }
        __syncthreads();
    }

    // ---- exact fp32 rescore: wave w handles candidates w, w+4, ... ----
    for (int c = w; c < CSEL; c += 4) {
        int idx = cIdx[c];
        const float4* kr = (const float4*)(keys + (size_t)idx * D);
        const float4* qr = (const float4*)qrow;
        float4 k1 = kr[lane], k2 = kr[lane + 64];
        float4 q1 = qr[lane], q2 = qr[lane + 64];
        float p = q1.x*k1.x + q1.y*k1.y + q1.z*k1.z + q1.w*k1.w
                + q2.x*k2.x + q2.y*k2.y + q2.z*k2.z + q2.w*k2.w;
#pragma unroll
        for (int off = 32; off; off >>= 1) p += __shfl_xor(p, off);
        if (lane == 0) cS[c] = p * kscale[idx];
    }
    __syncthreads();

    if (t == 0) {                                // exact top-16 + softmax weights
        float s[CSEL]; int id[CSEL];
        for (int i = 0; i < CSEL; ++i) { s[i] = cS[i]; id[i] = cIdx[i]; }
        float selS[K]; int selI[K];
        for (int r = 0; r < K; ++r) {
            float bb = -INFINITY; int bbi = 0x7fffffff, bbp = -1;
            for (int i = 0; i < CSEL; ++i)
                if (s[i] > bb || (s[i] == bb && id[i] < bbi)) { bb = s[i]; bbi = id[i]; bbp = i; }
            selS[r] = bb; selI[r] = bbi; s[bbp] = -INFINITY;
        }
        float y[K], e[K];
        for (int k = 0; k < K; ++k) y[k] = selS[k] / 0.1f;
        float ymax = y[0];                       // sorted desc
        float Z = 0.f;
        for (int k = 0; k < K; ++k) { e[k] = expf(y[k] - ymax); Z += e[k]; }
        float Z2 = 0.f;
        for (int k = 0; k < K; ++k) {
            float ww = e[k] / Z;
            if (!(selS[k] >= 0.0f)) ww = 0.f;
            e[k] = ww; Z2 += ww;
        }
        for (int k = 0; k < K; ++k) { wgt[k] = e[k] / (Z2 + 1e-8f); wIdx[k] = selI[k]; }
    }
    __syncthreads();

    for (int e0 = t; e0 < HF; e0 += 256) {
        float o = 0.f;
#pragma unroll
        for (int k = 0; k < K; ++k)
            o += wgt[k] * values[(size_t)wIdx[k] * HF + e0];
        out[(size_t)b * HF + e0] = o;
    }
}

extern "C" void kernel_launch(void* const* d_in, const int* in_sizes, int n_in,
                              void* d_out, int out_size, void* d_ws, size_t ws_size,
                              hipStream_t stream) {
    const float* query  = (const float*)d_in[0];
    const float* keys   = (const float*)d_in[1];
    const float* values = (const float*)d_in[2];
    const int*   ts     = (const int*)d_in[3];
    const int*   gstep  = (const int*)d_in[4];
    float* out = (float*)d_out;

    // workspace carve-out (256B aligned); total ~119 MB
    char* p = (char*)d_ws;
    size_t o = 0;
    auto alloc = [&](size_t bytes) { char* r = p + o; o = (o + bytes + 255) & ~(size_t)255; return r; };
    float*          qn     = (float*)alloc((size_t)B * D * 4);
    unsigned short* qb     = (unsigned short*)alloc((size_t)B * D * 2);
    float*          kscale = (float*)alloc((size_t)N * 4);
    unsigned short* kb     = (unsigned short*)alloc((size_t)NPAD * D * 2);
    float*          gmax   = (float*)alloc((size_t)B * NG * 4);

    prep_q<<<B / 4, 256, 0, stream>>>(query, qn, qb);
    prep_k<<<NPAD / 4, 256, 0, stream>>>(keys, ts, gstep, kscale, kb);
    dim3 g2(B / QT, NKT);
    gmax_k<<<g2, 256, 0, stream>>>(qb, kb, gmax);
    select_out<<<B, 256, 0, stream>>>(gmax, qb, kb, qn, keys, kscale, values, out);
}